// Round 2
// baseline (4103.348 us; speedup 1.0000x reference)
//
#include <hip/hip_runtime.h>
#include <hip/hip_bf16.h>

using u16 = unsigned short;
using u32 = unsigned int;

typedef __bf16 bf16x8 __attribute__((ext_vector_type(8)));
typedef float  f32x4v __attribute__((ext_vector_type(4)));
typedef u16    u16x8  __attribute__((ext_vector_type(8)));

constexpr int B_   = 8192;
constexpr int T_   = 34;
constexpr int DMHC = 64;
constexpr int PEP  = 320;
constexpr int NPER = 24;
constexpr int NN   = B_ * NPER;   // 196608 nodes
constexpr int NHE  = 65536;       // hyperedges
constexpr int NE   = NN * 3;      // 589824 edges

// ---------- helpers ----------
__device__ inline u16 f2bf(float f) {
    return __builtin_bit_cast(u16, __float2bfloat16(f));
}
__device__ inline float bf2f(u32 lo16) {
    return __builtin_bit_cast(float, lo16 << 16);
}
__device__ inline bf16x8 ldfrag(const u16* p) {
    return __builtin_bit_cast(bf16x8, *reinterpret_cast<const int4*>(p));
}
__device__ inline f32x4v mfma16(bf16x8 a, bf16x8 b, f32x4v c) {
    return __builtin_amdgcn_mfma_f32_16x16x32_bf16(a, b, c, 0, 0, 0);
}
// stage 8 elements into LDS as bf16
__device__ inline void stage8(u16* dst, const float* src) {
    float4 a = *reinterpret_cast<const float4*>(src);
    float4 b = *reinterpret_cast<const float4*>(src + 4);
    u16x8 t;
    t[0]=f2bf(a.x); t[1]=f2bf(a.y); t[2]=f2bf(a.z); t[3]=f2bf(a.w);
    t[4]=f2bf(b.x); t[5]=f2bf(b.y); t[6]=f2bf(b.z); t[7]=f2bf(b.w);
    *reinterpret_cast<u16x8*>(dst) = t;
}
__device__ inline void stage8(u16* dst, const u16* src) {
    *reinterpret_cast<int4*>(dst) = *reinterpret_cast<const int4*>(src);
}
__device__ inline float sigf(float x)  { return 1.0f / (1.0f + __expf(-x)); }
__device__ inline float tanhf_fast(float x) {
    x = fminf(fmaxf(x, -15.0f), 15.0f);
    float e = __expf(-2.0f * x);
    return (1.0f - e) / (1.0f + e);
}
__device__ inline void atomAddF(float* p, float v) { unsafeAtomicAdd(p, v); }

// ---------- LSTM (one layer, both directions via grid.y) ----------
// Each block: 32 batch rows, 4 waves; wave w owns gate units u in [16w,16w+16).
// Weights as MFMA B-fragments in registers; h/c state in registers; h fed back
// via LDS (bf16) each step. Output (B,T,128) bf16, fwd cols 0..63, bwd 64..127.
template<typename XT, int DIN>
__global__ __launch_bounds__(256) void lstm_kernel(
    const XT* __restrict__ xin,
    const float* __restrict__ wih_f, const float* __restrict__ whh_f,
    const float* __restrict__ bih_f, const float* __restrict__ bhh_f,
    const float* __restrict__ wih_b, const float* __restrict__ whh_b,
    const float* __restrict__ bih_b, const float* __restrict__ bhh_b,
    u16* __restrict__ hout)
{
    const int dir  = blockIdx.y;
    const float* wih = dir ? wih_b : wih_f;
    const float* whh = dir ? whh_b : whh_f;
    const float* bih = dir ? bih_b : bih_f;
    const float* bhh = dir ? bhh_b : bhh_f;
    const int b0   = blockIdx.x * 32;
    const int tid  = threadIdx.x;
    const int wv   = tid >> 6;
    const int lane = tid & 63;
    const int l15  = lane & 15;
    const int lhi  = lane >> 4;

    __shared__ u16 xs[32][DIN];
    __shared__ u16 hs[32][64];

    // Weight fragments (loaded once)
    bf16x8 bihf[4][DIN / 32];
    bf16x8 bhhf[4][2];
#pragma unroll
    for (int g = 0; g < 4; ++g) {
        const int nrow = 64 * g + 16 * wv + l15;
#pragma unroll
        for (int kt = 0; kt < DIN / 32; ++kt) {
            const float* s = wih + (size_t)nrow * DIN + kt * 32 + lhi * 8;
            u16x8 t;
#pragma unroll
            for (int e = 0; e < 8; ++e) t[e] = f2bf(s[e]);
            bihf[g][kt] = __builtin_bit_cast(bf16x8, t);
        }
#pragma unroll
        for (int kt = 0; kt < 2; ++kt) {
            const float* s = whh + (size_t)nrow * 64 + kt * 32 + lhi * 8;
            u16x8 t;
#pragma unroll
            for (int e = 0; e < 8; ++e) t[e] = f2bf(s[e]);
            bhhf[g][kt] = __builtin_bit_cast(bf16x8, t);
        }
    }
    float bias[4];
#pragma unroll
    for (int g = 0; g < 4; ++g) {
        int n = 64 * g + 16 * wv + l15;
        bias[g] = bih[n] + bhh[n];
    }

    float cst[2][4], hp[2][4];
#pragma unroll
    for (int mt = 0; mt < 2; ++mt)
#pragma unroll
        for (int r = 0; r < 4; ++r) { cst[mt][r] = 0.f; hp[mt][r] = 0.f; }

    for (int t = 0; t <= T_; ++t) {
        __syncthreads();
        // write h_{t-1} (or zeros at t=0) into hs
#pragma unroll
        for (int mt = 0; mt < 2; ++mt)
#pragma unroll
            for (int r = 0; r < 4; ++r)
                hs[mt * 16 + lhi * 4 + r][16 * wv + l15] = f2bf(hp[mt][r]);
        // stage x_t
        if (t < T_) {
            const int tt = dir ? (T_ - 1 - t) : t;
            if constexpr (DIN == 64) {
                int m = tid >> 3, k0 = (tid & 7) * 8;
                stage8(&xs[m][k0], xin + ((size_t)(b0 + m) * T_ + tt) * DIN + k0);
            } else {
                int m = tid >> 3, k0 = (tid & 7) * 16;
                const XT* src = xin + ((size_t)(b0 + m) * T_ + tt) * DIN + k0;
                stage8(&xs[m][k0], src);
                stage8(&xs[m][k0 + 8], src + 8);
            }
        }
        __syncthreads();
        // coalesced global write of h_{t-1}
        if (t > 0) {
            const int tprev = dir ? (T_ - t) : (t - 1);
            int m = tid >> 3, k0 = (tid & 7) * 8;
            int4 v = *reinterpret_cast<const int4*>(&hs[m][k0]);
            *reinterpret_cast<int4*>(
                &hout[((size_t)(b0 + m) * T_ + tprev) * 128 + dir * 64 + k0]) = v;
        }
        if (t == T_) break;

        // A fragments
        bf16x8 ax[2][DIN / 32], ah[2][2];
#pragma unroll
        for (int mt = 0; mt < 2; ++mt) {
#pragma unroll
            for (int kt = 0; kt < DIN / 32; ++kt)
                ax[mt][kt] = ldfrag(&xs[mt * 16 + l15][kt * 32 + lhi * 8]);
#pragma unroll
            for (int kt = 0; kt < 2; ++kt)
                ah[mt][kt] = ldfrag(&hs[mt * 16 + l15][kt * 32 + lhi * 8]);
        }
#pragma unroll
        for (int mt = 0; mt < 2; ++mt) {
            f32x4v acc[4];
#pragma unroll
            for (int g = 0; g < 4; ++g) acc[g] = f32x4v{bias[g], bias[g], bias[g], bias[g]};
#pragma unroll
            for (int g = 0; g < 4; ++g) {
#pragma unroll
                for (int kt = 0; kt < DIN / 32; ++kt)
                    acc[g] = mfma16(ax[mt][kt], bihf[g][kt], acc[g]);
#pragma unroll
                for (int kt = 0; kt < 2; ++kt)
                    acc[g] = mfma16(ah[mt][kt], bhhf[g][kt], acc[g]);
            }
#pragma unroll
            for (int r = 0; r < 4; ++r) {
                float iv = sigf(acc[0][r]);
                float fv = sigf(acc[1][r]);
                float gv = tanhf_fast(acc[2][r]);
                float ov = sigf(acc[3][r]);
                float cv = fv * cst[mt][r] + iv * gv;
                cst[mt][r] = cv;
                hp[mt][r] = ov * tanhf_fast(cv);
            }
        }
    }
}

// ---------- GEMM: C(MxN) = A(MxK) @ W(NxK)^T (+bias), bf16 MFMA ----------
template<typename AT, typename OT, bool HAS_BIAS>
__global__ __launch_bounds__(256) void gemm_bt(
    const AT* __restrict__ A, const float* __restrict__ W,
    OT* __restrict__ C, const float* __restrict__ bias,
    int M, int N, int K)
{
    __shared__ u16 As[64][40];
    __shared__ u16 Ws[64][40];
    const int tid = threadIdx.x;
    const int m0 = blockIdx.x * 64, n0 = blockIdx.y * 64;
    const int wv = tid >> 6, lane = tid & 63, l15 = lane & 15, lhi = lane >> 4;
    const int wr = wv >> 1, wc = wv & 1;

    f32x4v acc[2][2] = {};
    const int r = tid >> 2, c0 = (tid & 3) * 8;
    for (int kb = 0; kb < K; kb += 32) {
        __syncthreads();
        stage8(&As[r][c0], A + (size_t)(m0 + r) * K + kb + c0);
        stage8(&Ws[r][c0], W + (size_t)(n0 + r) * K + kb + c0);
        __syncthreads();
        bf16x8 af[2], bfr[2];
#pragma unroll
        for (int i = 0; i < 2; ++i) {
            af[i]  = ldfrag(&As[wr * 32 + i * 16 + l15][lhi * 8]);
            bfr[i] = ldfrag(&Ws[wc * 32 + i * 16 + l15][lhi * 8]);
        }
#pragma unroll
        for (int i = 0; i < 2; ++i)
#pragma unroll
            for (int j = 0; j < 2; ++j)
                acc[i][j] = mfma16(af[i], bfr[j], acc[i][j]);
    }
#pragma unroll
    for (int i = 0; i < 2; ++i)
#pragma unroll
        for (int j = 0; j < 2; ++j) {
            const int mrow = m0 + wr * 32 + i * 16 + lhi * 4;
            const int ncol = n0 + wc * 32 + j * 16 + l15;
            float bv = 0.f;
            if constexpr (HAS_BIAS) bv = bias[ncol];
#pragma unroll
            for (int rr = 0; rr < 4; ++rr) {
                float v = acc[i][j][rr] + bv;
                if constexpr (__is_same(OT, float)) {
                    C[(size_t)(mrow + rr) * N + ncol] = v;
                } else {
                    C[(size_t)(mrow + rr) * N + ncol] = f2bf(v);
                }
            }
        }
}

// ---------- hypergraph degree / scatter ----------
__global__ void deg_count(const int* __restrict__ row, const int* __restrict__ col,
                          float* __restrict__ dv, float* __restrict__ de)
{
    int e = blockIdx.x * 256 + threadIdx.x;
    atomAddF(&dv[row[e]], 1.0f);
    atomAddF(&de[col[e]], 1.0f);
}
__global__ void inv_kernel(float* __restrict__ p)
{
    int i = blockIdx.x * 256 + threadIdx.x;
    float v = p[i];
    p[i] = v > 0.f ? 1.0f / v : 0.0f;
}
// e_feat[col[e]] += xt[row[e]]   (wave per edge)
__global__ void scatter_he(const int* __restrict__ row, const int* __restrict__ col,
                           const float* __restrict__ xt, float* __restrict__ ef)
{
    int e = blockIdx.x * 4 + (threadIdx.x >> 6);
    int lane = threadIdx.x & 63;
    const float* src = xt + (size_t)row[e] * PEP;
    float* dst = ef + (size_t)col[e] * PEP;
#pragma unroll
    for (int j = 0; j < 5; ++j) {
        int f = lane + 64 * j;
        atomAddF(&dst[f], src[f]);
    }
}
// acc[row[e]] += e_feat[col[e]] * b_inv[col[e]]
__global__ void scatter_node(const int* __restrict__ row, const int* __restrict__ col,
                             const float* __restrict__ ef, const float* __restrict__ binv,
                             float* __restrict__ acc)
{
    int e = blockIdx.x * 4 + (threadIdx.x >> 6);
    int lane = threadIdx.x & 63;
    int c = col[e];
    float bi = binv[c];
    const float* src = ef + (size_t)c * PEP;
    float* dst = acc + (size_t)row[e] * PEP;
#pragma unroll
    for (int j = 0; j < 5; ++j) {
        int f = lane + 64 * j;
        atomAddF(&dst[f], src[f] * bi);
    }
}
template<bool RELU>
__global__ void finalize_node(const float* __restrict__ acc, const float* __restrict__ dinv,
                              const float* __restrict__ bias, u16* __restrict__ outb)
{
    int v = blockIdx.x, f = threadIdx.x;
    float val = acc[(size_t)v * PEP + f] * dinv[v] + bias[f];
    if (RELU) val = fmaxf(val, 0.0f);
    outb[(size_t)v * PEP + f] = f2bf(val);
}

// ---------- fused head: clus_map + fc1 + out ----------
__global__ __launch_bounds__(256) void clus_head(
    const u16* __restrict__ mhc,   // (B,T,128) bf16
    const u16* __restrict__ pep,   // (B,24,128) bf16
    const float* __restrict__ fc1w, const float* __restrict__ fc1b,
    const float* __restrict__ outw, const float* __restrict__ outb,
    float* __restrict__ dout)
{
    const int b = blockIdx.x, tid = threadIdx.x;
    __shared__ u32 sm[T_ * 64];
    __shared__ u32 sp[NPER * 64];
    __shared__ float scm[T_ * NPER];
    __shared__ float sxc[16];

    const u32* gm = reinterpret_cast<const u32*>(mhc + (size_t)b * T_ * 128);
    for (int i = tid; i < T_ * 64; i += 256) sm[i] = gm[i];
    const u32* gp = reinterpret_cast<const u32*>(pep + (size_t)b * NPER * 128);
    for (int i = tid; i < NPER * 64; i += 256) sp[i] = gp[i];
    __syncthreads();

    for (int o = tid; o < T_ * NPER; o += 256) {
        int t = o / NPER, n = o - t * NPER;
        const u32* mr = sm + t * 64;
        const u32* pr = sp + n * 64;
        float s = 0.f;
#pragma unroll 8
        for (int k = 0; k < 64; ++k) {
            u32 a = mr[k], p = pr[k];
            s += bf2f(a & 0xffffu) * bf2f(p & 0xffffu);
            s += bf2f(a >> 16) * bf2f(p >> 16);
        }
        dout[(size_t)B_ + (size_t)b * (T_ * NPER) + o] = s;
        scm[o] = s;
    }
    __syncthreads();

    const int o = tid >> 4, j0 = tid & 15;
    float part = 0.f;
    for (int j = j0; j < T_ * NPER; j += 16) part += scm[j] * fc1w[o * (T_ * NPER) + j];
#pragma unroll
    for (int off = 8; off; off >>= 1) part += __shfl_xor(part, off);
    if (j0 == 0) sxc[o] = fmaxf(part + fc1b[o], 0.0f);
    __syncthreads();
    if (tid == 0) {
        float s = outb[0];
#pragma unroll
        for (int oo = 0; oo < 16; ++oo) s += sxc[oo] * outw[oo];
        dout[b] = s;
    }
}

// ---------- launch ----------
extern "C" void kernel_launch(void* const* d_in, const int* in_sizes, int n_in,
                              void* d_out, int out_size, void* d_ws, size_t ws_size,
                              hipStream_t stream)
{
    const float* x     = (const float*)d_in[0];
    const int*   ei    = (const int*)d_in[1];
    const float* mhc   = (const float*)d_in[2];
    const float* wih0f = (const float*)d_in[3];
    const float* whh0f = (const float*)d_in[4];
    const float* bih0f = (const float*)d_in[5];
    const float* bhh0f = (const float*)d_in[6];
    const float* wih0b = (const float*)d_in[7];
    const float* whh0b = (const float*)d_in[8];
    const float* bih0b = (const float*)d_in[9];
    const float* bhh0b = (const float*)d_in[10];
    const float* wih1f = (const float*)d_in[11];
    const float* whh1f = (const float*)d_in[12];
    const float* bih1f = (const float*)d_in[13];
    const float* bhh1f = (const float*)d_in[14];
    const float* wih1b = (const float*)d_in[15];
    const float* whh1b = (const float*)d_in[16];
    const float* bih1b = (const float*)d_in[17];
    const float* bhh1b = (const float*)d_in[18];
    const float* hc1w  = (const float*)d_in[19];
    const float* hc1b  = (const float*)d_in[20];
    const float* hc2w  = (const float*)d_in[21];
    const float* hc2b  = (const float*)d_in[22];
    const float* pepw  = (const float*)d_in[23];
    const float* pepbias = (const float*)d_in[24];
    const float* fc1w  = (const float*)d_in[25];
    const float* fc1b  = (const float*)d_in[26];
    const float* outw  = (const float*)d_in[27];
    const float* outbv = (const float*)d_in[28];
    const int* row = ei;
    const int* col = ei + NE;
    float* dout = (float*)d_out;

    char* w = (char*)d_ws;
    size_t off = 0;
    auto alloc = [&](size_t bytes) {
        size_t r = off;
        off += (bytes + 255) & ~(size_t)255;
        return r;
    };
    u16*   L0   = (u16*)  (w + alloc((size_t)B_ * T_ * 128 * 2));
    u16*   L1   = (u16*)  (w + alloc((size_t)B_ * T_ * 128 * 2));
    float* bufF = (float*)(w + alloc((size_t)NN * PEP * 4));
    float* bufE = (float*)(w + alloc((size_t)NHE * PEP * 4));
    u16*   xgb  = (u16*)  (w + alloc((size_t)NN * PEP * 2));
    u16*   pepb = (u16*)  (w + alloc((size_t)B_ * NPER * 128 * 2));
    float* dinv = (float*)(w + alloc((size_t)NN * 4));
    float* binv = (float*)(w + alloc((size_t)NHE * 4));
    (void)ws_size; (void)in_sizes; (void)n_in; (void)out_size; (void)binv;

    // LSTM layer 0 then layer 1 (both directions via grid.y)
    lstm_kernel<float, 64><<<dim3(B_ / 32, 2), 256, 0, stream>>>(
        mhc, wih0f, whh0f, bih0f, bhh0f, wih0b, whh0b, bih0b, bhh0b, L0);
    lstm_kernel<u16, 128><<<dim3(B_ / 32, 2), 256, 0, stream>>>(
        L0, wih1f, whh1f, bih1f, bhh1f, wih1b, whh1b, bih1b, bhh1b, L1);

    // degrees
    hipMemsetAsync(dinv, 0, (size_t)(NN + NHE) * 4, stream);
    deg_count<<<NE / 256, 256, 0, stream>>>(row, col, dinv, binv);
    inv_kernel<<<(NN + NHE) / 256, 256, 0, stream>>>(dinv);

    // hyperconv 1
    hipMemsetAsync(bufE, 0, (size_t)NHE * PEP * 4, stream);
    gemm_bt<float, float, false><<<dim3(NN / 64, PEP / 64), 256, 0, stream>>>(
        x, hc1w, bufF, nullptr, NN, PEP, PEP);
    scatter_he<<<NE / 4, 256, 0, stream>>>(row, col, bufF, bufE);
    hipMemsetAsync(bufF, 0, (size_t)NN * PEP * 4, stream);
    scatter_node<<<NE / 4, 256, 0, stream>>>(row, col, bufE, binv, bufF);
    finalize_node<true><<<NN, PEP, 0, stream>>>(bufF, dinv, hc1b, xgb);

    // hyperconv 2
    hipMemsetAsync(bufE, 0, (size_t)NHE * PEP * 4, stream);
    gemm_bt<u16, float, false><<<dim3(NN / 64, PEP / 64), 256, 0, stream>>>(
        xgb, hc2w, bufF, nullptr, NN, PEP, PEP);
    scatter_he<<<NE / 4, 256, 0, stream>>>(row, col, bufF, bufE);
    hipMemsetAsync(bufF, 0, (size_t)NN * PEP * 4, stream);
    scatter_node<<<NE / 4, 256, 0, stream>>>(row, col, bufE, binv, bufF);
    finalize_node<false><<<NN, PEP, 0, stream>>>(bufF, dinv, hc2b, xgb);

    // pep_fc
    gemm_bt<u16, u16, true><<<dim3(NN / 64, 128 / 64), 256, 0, stream>>>(
        xgb, pepw, pepb, pepbias, NN, 128, PEP);

    // fused clus_map + fc1 + out
    clus_head<<<B_, 256, 0, stream>>>(L1, pepb, fc1w, fc1b, outw, outbv, dout);
}